// Round 6
// baseline (549.721 us; speedup 1.0000x reference)
//
#include <hip/hip_runtime.h>
#include <math.h>

#define NH 12
#define HD 32
#define GN 48
#define TK 96
#define NB 2
#define NN 1600
#define CC 384
#define BHN (NB*NH)          // 24
#define QKV_COLS (3*NH*HD)   // 1152
#define NQ (BHN*NN)          // 38400 total (b,h,n) queries
#define KP 36                // padded K row: bank-quad = 4*((row+chunk)%8)
#define LPW 68               // LDS row pad: 68%32=4 -> write/read aliasing is 2-way (free)
#define WREG (16*LPW*2)      // per-wave LDS region: As(16x68) + Bs(16x68) = 2176 floats

// ---------------------------------------------------------------------------
// GEMM-W2 (round 6): out = A[M,K] @ B[N,K]^T. 64x64 tile, 8x8 micro,
// TWO waves per block with K SPLIT ACROSS WAVES (wave w: k in [w*K/2,(w+1)*K/2))
// each in its OWN LDS buffer -> zero barriers in the main loop.
//  - LDS-balance model (R0-R5 plateau explained): micro rm x rn consumes
//    (rm+rn)*4B per rm*rn FMAs; LDS feeds 4 SIMDs at <=128 B/cy. Only 8x8
//    (1 B/FMA) balances LDS vs full VALU issue. 4x8 (R5) ceils at 67%/44%.
//  - 8x8 needs TLP too: R3's 1-wave 64x64 grid = 0.88 waves/SIMD, latency-
//    exposed at 41%. K-split doubles waves: QKV 900 blocks x 2 = 1.76/SIMD,
//    each wave fully independent until the 2-term reduction epilogue.
//  - Reduction acc_w0 + acc_w1 in fixed order (deterministic); reuses the
//    17.4KB tile LDS as scratch (>= 16KB needed).
// MODE 0: scatter epilogue into q/k/v [B,h,N,d]   MODE 1: plain store [M,N]
// ---------------------------------------------------------------------------
template<int MODE>
__global__ __launch_bounds__(128, 2)
void gemm_w2(const float* __restrict__ A, const float* __restrict__ B,
             float* __restrict__ o0, float* __restrict__ o1, float* __restrict__ o2,
             int M, int N, int K)
{
    __shared__ float S[2*WREG];       // [wave][As 16x68 | Bs 16x68], 17408 B
    const int tid = threadIdx.x;      // 0..127
    const int w = tid >> 6;           // wave 0/1
    const int lane = tid & 63;
    const int tx = lane & 7, ty = lane >> 3;
    const int m0 = blockIdx.y * 64, n0 = blockIdx.x * 64;

    float* __restrict__ As = S + w*WREG;            // As[k][r] = As[k*LPW + r]
    float* __restrict__ Bs = As + 16*LPW;

    const int KH = K >> 1;            // 192
    const int kbeg = w * KH;

    // staging map (R3-proven): thread covers row srow+16c, k-seg scol..scol+3
    const int srow = lane >> 2;       // 0..15
    const int scol = (lane & 3) * 4;  // 0,4,8,12
    const float* __restrict__ Ap = &A[(m0 + srow) * K + kbeg + scol];
    const float* __restrict__ Bp = &B[(n0 + srow) * K + kbeg + scol];
    const int rstep = 16 * K;

    float acc[8][8] = {};

    // prologue: stage tile 0 of this wave's k-range
    {
        #pragma unroll
        for (int c = 0; c < 4; ++c) {
            float4 a = *(const float4*)(Ap + c*rstep);
            float4 b = *(const float4*)(Bp + c*rstep);
            int r = c*16 + srow;
            As[(scol+0)*LPW + r] = a.x; As[(scol+1)*LPW + r] = a.y;
            As[(scol+2)*LPW + r] = a.z; As[(scol+3)*LPW + r] = a.w;
            Bs[(scol+0)*LPW + r] = b.x; Bs[(scol+1)*LPW + r] = b.y;
            Bs[(scol+2)*LPW + r] = b.z; Bs[(scol+3)*LPW + r] = b.w;
        }
    }
    // no barrier: each wave owns its buffer; DS ops wave-ordered

    for (int k0 = 16; k0 <= KH; k0 += 16) {
        // 1) issue next-tile global loads first — hide under the FMA block
        const bool more = (k0 < KH);
        float4 an[4], bn[4];
        if (more) {
            #pragma unroll
            for (int c = 0; c < 4; ++c) {
                an[c] = *(const float4*)(Ap + c*rstep + k0);
                bn[c] = *(const float4*)(Bp + c*rstep + k0);
            }
        }
        // 2) compute current tile: 16 kk x 64 FMA per lane, 4 ds_read_b128/kk
        #pragma unroll
        for (int kk = 0; kk < 16; ++kk) {
            float4 A0 = *(const float4*)&As[kk*LPW + ty*8];     // 8-addr bcast
            float4 A1 = *(const float4*)&As[kk*LPW + ty*8 + 4];
            float4 B0 = *(const float4*)&Bs[kk*LPW + tx*8];
            float4 B1 = *(const float4*)&Bs[kk*LPW + tx*8 + 4];
            float ar[8] = {A0.x, A0.y, A0.z, A0.w, A1.x, A1.y, A1.z, A1.w};
            float br[8] = {B0.x, B0.y, B0.z, B0.w, B1.x, B1.y, B1.z, B1.w};
            #pragma unroll
            for (int i = 0; i < 8; ++i)
                #pragma unroll
                for (int j = 0; j < 8; ++j)
                    acc[i][j] = fmaf(ar[i], br[j], acc[i][j]);
        }
        // 3) overwrite own buffer — wave-ordered DS, no barrier
        if (more) {
            #pragma unroll
            for (int c = 0; c < 4; ++c) {
                int r = c*16 + srow;
                As[(scol+0)*LPW + r] = an[c].x; As[(scol+1)*LPW + r] = an[c].y;
                As[(scol+2)*LPW + r] = an[c].z; As[(scol+3)*LPW + r] = an[c].w;
                Bs[(scol+0)*LPW + r] = bn[c].x; Bs[(scol+1)*LPW + r] = bn[c].y;
                Bs[(scol+2)*LPW + r] = bn[c].z; Bs[(scol+3)*LPW + r] = bn[c].w;
            }
        }
    }

    // ---- cross-wave reduction: out = acc_w0 + acc_w1 (fixed order) ----
    __syncthreads();                  // both waves done with tile buffers
    if (w == 1) {
        #pragma unroll
        for (int i = 0; i < 8; ++i)
            #pragma unroll
            for (int j = 0; j < 8; ++j)
                S[(i*8 + j)*64 + lane] = acc[i][j];   // bank = lane%32: free
    }
    __syncthreads();
    if (w == 1) return;

    #pragma unroll
    for (int i = 0; i < 8; ++i)
        #pragma unroll
        for (int j = 0; j < 8; ++j)
            acc[i][j] += S[(i*8 + j)*64 + lane];      // low-k + high-k

    if (MODE == 0) {
        // 64 | 384: the tile's 64 cols lie inside exactly one of q/k/v
        const int which = n0 / CC;
        const int rembase = n0 - which * CC + tx*8;
        float* __restrict__ dst = (which == 0) ? o0 : (which == 1) ? o1 : o2;
        #pragma unroll
        for (int i = 0; i < 8; ++i) {
            int row = m0 + ty*8 + i;
            int b  = row / NN;
            int nn = row - b * NN;
            #pragma unroll
            for (int jn = 0; jn < 2; ++jn) {
                int rem = rembase + jn*4;          // stays inside one head
                int hh = rem >> 5, dd = rem & 31;
                float4 st = make_float4(acc[i][jn*4+0], acc[i][jn*4+1],
                                        acc[i][jn*4+2], acc[i][jn*4+3]);
                *(float4*)&dst[((b*NH + hh)*NN + nn)*HD + dd] = st;
            }
        }
    } else {
        #pragma unroll
        for (int i = 0; i < 8; ++i) {
            int row = m0 + ty*8 + i;
            #pragma unroll
            for (int jn = 0; jn < 2; ++jn) {
                float4 st = make_float4(acc[i][jn*4+0], acc[i][jn*4+1],
                                        acc[i][jn*4+2], acc[i][jn*4+3]);
                *(float4*)&o0[row * N + n0 + tx*8 + jn*4] = st;
            }
        }
    }
}

// ---------------------------------------------------------------------------
// Kernel 2: per-query group argmax (gidx), strict > == jnp.argmax tie-break
// ---------------------------------------------------------------------------
__global__ __launch_bounds__(256)
void group_route(const float* __restrict__ q, const float* __restrict__ wgp,
                 int* __restrict__ gidx)
{
    int t = blockIdx.x * 256 + threadIdx.x;   // [0, NQ)
    int bh = t / NN;
    int hh = bh % NH;
    const float* qp = q + t * HD;
    float qr[HD];
    #pragma unroll
    for (int i = 0; i < HD; i += 4) {
        float4 x = *(const float4*)&qp[i];
        qr[i] = x.x; qr[i+1] = x.y; qr[i+2] = x.z; qr[i+3] = x.w;
    }
    float best = -INFINITY; int bg = 0;
    for (int g = 0; g < GN; ++g) {
        const float* gp = wgp + hh*GN*HD + g*HD;
        float s = 0.f;
        #pragma unroll
        for (int i = 0; i < HD; i += 4) {
            float4 w = *(const float4*)&gp[i];
            s += qr[i]*w.x + qr[i+1]*w.y + qr[i+2]*w.z + qr[i+3]*w.w;
        }
        if (s > best) { best = s; bg = g; }
    }
    gidx[t] = bg;
}

// ---------------------------------------------------------------------------
// Kernel 3a (v4): per-(bh,g) deterministic group-mean, branchless always-load
// + query bucketing (qperm/qoff/qcnt). 1152 blocks.
// ---------------------------------------------------------------------------
__global__ __launch_bounds__(256)
void qmean_all2(const float* __restrict__ q, const int* __restrict__ gidx,
                float* __restrict__ qmean, int* __restrict__ qperm,
                int* __restrict__ qoff, int* __restrict__ qcnt)
{
    __shared__ float part[8][HD];
    __shared__ int   cnts[8];
    __shared__ int   off_s, pos_s;
    const int bid = blockIdx.x;       // bh*GN + g
    const int g = bid % GN, bh = bid / GN;
    const int tid = threadIdx.x;
    const int s = tid >> 5, dd = tid & 31;

    const int* __restrict__ gx = gidx + bh*NN;
    const float* __restrict__ qb = q + bh*NN*HD;

    if (tid == 0) { off_s = 0; pos_s = 0; }

    const int base = s * 200;         // 1600/8 rows per slice, contiguous
    float p = 0.f; int c = 0;
    #pragma unroll 2
    for (int n0 = 0; n0 < 200; n0 += 4) {
        int4 g4 = *(const int4*)&gx[base + n0];
        float v0 = qb[(base+n0+0)*HD + dd];   // unconditional: pipelines
        float v1 = qb[(base+n0+1)*HD + dd];
        float v2 = qb[(base+n0+2)*HD + dd];
        float v3 = qb[(base+n0+3)*HD + dd];
        if (g4.x == g) { p += v0; c++; }      // cndmask+add, no branch
        if (g4.y == g) { p += v1; c++; }
        if (g4.z == g) { p += v2; c++; }
        if (g4.w == g) { p += v3; c++; }
    }
    part[s][dd] = p;
    if (dd == 0) cnts[s] = c;
    __syncthreads();                  // part[] + off_s/pos_s init visible

    if (tid < HD) {
        float sum = 0.f; int ct = 0;
        #pragma unroll
        for (int ss = 0; ss < 8; ++ss) { sum += part[ss][tid]; ct += cnts[ss]; }
        qmean[bid*HD + tid] = ct ? sum / (float)ct : 0.f;
    }

    // bucketing: offset = #queries in groups < g (gx row is L1-hot now)
    int mo = 0;
    for (int n = tid; n < NN; n += 256) mo += (gx[n] < g);
    atomicAdd(&off_s, mo);
    __syncthreads();
    for (int n = tid; n < NN; n += 256) {
        if (gx[n] == g) {
            int pp = atomicAdd(&pos_s, 1);
            qperm[bh*NN + off_s + pp] = n;
        }
    }
    __syncthreads();
    if (tid == 0) { qoff[bid] = off_s; qcnt[bid] = pos_s; }
}

// ---------------------------------------------------------------------------
// Kernel 3b: scores[bh*GN+g][n] = qmean[bh,g] . k[bh,n]. Thread owns one n,
// k-row in registers, qmean tile in LDS (broadcast reads), coalesced stores.
// ---------------------------------------------------------------------------
__global__ __launch_bounds__(256)
void score_all(const float* __restrict__ qmean, const float* __restrict__ k,
               float* __restrict__ scores)
{
    __shared__ float Qs[GN][HD];          // 6 KB
    const int bh = blockIdx.y;
    const int tid = threadIdx.x;
    const int n = blockIdx.x*256 + tid;
    for (int i = tid; i < GN*HD; i += 256)
        ((float*)Qs)[i] = qmean[bh*GN*HD + i];
    __syncthreads();
    if (n >= NN) return;
    const float* __restrict__ kp = k + (bh*NN + n)*HD;
    float4 kr[8];
    #pragma unroll
    for (int c = 0; c < 8; ++c) kr[c] = *(const float4*)&kp[c*4];
    for (int g = 0; g < GN; ++g) {
        float s = 0.f;
        #pragma unroll
        for (int c = 0; c < 8; ++c) {
            float4 qv = *(const float4*)&Qs[g][c*4];   // same-addr broadcast
            s += kr[c].x*qv.x + kr[c].y*qv.y + kr[c].z*qv.z + kr[c].w*qv.w;
        }
        scores[(bh*GN + g)*NN + n] = s;               // coalesced per g
    }
}

// ---------------------------------------------------------------------------
// Kernel 3c: per-WAVE barrier-free radix top-96. Each 64-lane wave owns one
// (bh,g) row of 1600 scores: keys + 256-bin hist live in per-wave LDS slices
// (DS ops from a wave complete in program order -> no __syncthreads).
// Suffix-scan in registers via shfl; pivot via ballot; collect via ballot-
// compaction in ascending index order (== lax.top_k lowest-index ties).
// ---------------------------------------------------------------------------
__global__ __launch_bounds__(256)
void topk_radix(const float* __restrict__ scores, int* __restrict__ topk)
{
    __shared__ unsigned keysL[4][NN];     // 25.6 KB
    __shared__ unsigned histL[4][256];    // 4 KB
    const int tid = threadIdx.x;
    const int w = tid >> 6, lane = tid & 63;
    const int gid = blockIdx.x*4 + w;     // (bh*GN + g) in [0,1152)
    const float* __restrict__ row = scores + gid*NN;
    unsigned* keys = keysL[w];
    unsigned* hist = histL[w];

    // load + order-preserving transform (1600 = 25*64 exactly)
    #pragma unroll
    for (int i = 0; i < 25; ++i) {
        int m = lane + 64*i;
        unsigned u = __float_as_uint(row[m]);
        u = (u & 0x80000000u) ? ~u : (u | 0x80000000u);
        keys[m] = u;
    }

    unsigned prefix = 0, r = TK;
    #pragma unroll
    for (int pass = 0; pass < 4; ++pass) {
        const int shift = 24 - 8*pass;
        #pragma unroll
        for (int j = 0; j < 4; ++j) hist[lane*4 + j] = 0;
        #pragma unroll
        for (int i = 0; i < 25; ++i) {
            unsigned u = keys[lane + 64*i];
            bool match = (pass == 0) || ((u >> (shift+8)) == (prefix >> (shift+8)));
            if (match) atomicAdd(&hist[(u >> shift) & 255u], 1u);
        }
        // suffix scan: lane holds bins 4L..4L+3
        uint4 h = *(const uint4*)&hist[lane*4];
        unsigned s3 = h.w, s2 = h.z + s3, s1 = h.y + s2, s0 = h.x + s1;
        unsigned I = s0;                      // inclusive suffix over lane totals
        #pragma unroll
        for (int off = 1; off < 64; off <<= 1) {
            unsigned t = __shfl_down(I, off);
            if (lane + off < 64) I += t;
        }
        unsigned E = I - s0;                  // strict suffix (lanes > L)
        unsigned sf[5] = {E+s0, E+s1, E+s2, E+s3, E};
        int bj = -1; unsigned subc = 0;
        #pragma unroll
        for (int j = 0; j < 4; ++j)
            if (sf[j] >= r && sf[j+1] < r) { bj = j; subc = sf[j+1]; }
        unsigned long long mask = __ballot(bj >= 0);   // exactly one bit set
        int src = __ffsll(mask) - 1;
        int bstar = __shfl(lane*4 + bj, src);
        unsigned sub = (unsigned)__shfl((int)subc, src);
        prefix |= ((unsigned)bstar) << shift;
        r -= sub;
    }
    const unsigned P = prefix;   // exact 96th-largest key; r = #equals to take

    // collect: all keys > P, then first r keys == P (ascending index)
    int* tko = topk + gid*TK;
    int base = 0;
    #pragma unroll
    for (int i = 0; i < 25; ++i) {
        int m = lane + 64*i;
        bool gt = (keys[m] > P);
        unsigned long long mask = __ballot(gt);
        if (gt) tko[base + __popcll(mask & ((1ull << lane) - 1ull))] = m;
        base += (int)__popcll(mask);
    }
    #pragma unroll
    for (int i = 0; i < 25; ++i) {
        int m = lane + 64*i;
        bool eq = (keys[m] == P);
        unsigned long long mask = __ballot(eq);
        if (eq) {
            int pos = base + (int)__popcll(mask & ((1ull << lane) - 1ull));
            if (pos < TK) tko[pos] = m;
        }
        base += (int)__popcll(mask);
    }
}

// ---------------------------------------------------------------------------
// Kernel 4 (v8): group-bucketed attention, shuffle-free phase 1 (padded Ks),
// LDS score buffer Ps, split-S. Verified round 12: dropped out of top-5.
// ---------------------------------------------------------------------------
__global__ __launch_bounds__(256)
void sparse_attn8(const float* __restrict__ q, const float* __restrict__ k,
                  const float* __restrict__ v, const int* __restrict__ topk,
                  const int* __restrict__ qperm, const int* __restrict__ qoff,
                  const int* __restrict__ qcnt, float* __restrict__ out)
{
    __shared__ float Ks[TK*KP];      // 13.8 KB (padded rows)
    __shared__ float Vs[TK*HD];      // 12 KB
    __shared__ float Ps[32][104];    // 13.3 KB, padded row (104%32==8)

    const int sub = blockIdx.x & 1;       // split-S half
    const int bid = blockIdx.x >> 1;      // bh*GN + g
    const int bh = bid / GN;
    const int nq = qcnt[bid];
    if (nq <= sub*32) return;             // this half has no work (uniform)
    const int off = qoff[bid];
    const int tid = threadIdx.x;

    const int* __restrict__ tk = topk + bid*TK;
    const float* __restrict__ kb = k + bh*NN*HD;
    const float* __restrict__ vb = v + bh*NN*HD;

    // stage K (padded) and V: 8 consecutive lanes fetch one 128B row
    for (int idx = tid; idx < TK*8; idx += 256) {
        int row = idx >> 3, ch = idx & 7;
        int r = tk[row];
        *(float4*)&Ks[row*KP + ch*4] = *(const float4*)&kb[r*HD + ch*4];
        ((float4*)Vs)[idx] = *(const float4*)&vb[r*HD + ch*4];
    }
    __syncthreads();

    const float scale = 0.17677669529663687f;   // 32^-0.5
    const int qs = tid >> 3;            // query slot 0..31 (Ps row owner)
    const int dl = tid & 7;             // lane in 8-lane group
    const int b = bh / NH, hh = bh - b*NH;
    const float* __restrict__ qbase = q + bh*NN*HD;
    const int* __restrict__ qlist = qperm + bh*NN + off;

    for (int it0 = sub*32; it0 < nq; it0 += 64) {
        const int qi = it0 + qs;
        const bool act = (qi < nq);
        const int nn = qlist[act ? qi : nq-1];   // safe clamp; group-uniform

        // full q row (8-lane same-address reads: one cache line per group)
        float4 qr[8];
        #pragma unroll
        for (int c = 0; c < 8; ++c) qr[c] = *(const float4*)&qbase[nn*HD + c*4];

        // phase 1: lane dl fully scores keys t*8+dl -> Ps[qs][j]; no shuffles
        #pragma unroll 2
        for (int t = 0; t < 12; ++t) {
            const int j = t*8 + dl;
            float s0 = 0.f, s1 = 0.f, s2 = 0.f, s3 = 0.f;
            #pragma unroll
            for (int c = 0; c < 8; ++c) {
                float4 w = *(const float4*)&Ks[j*KP + c*4];
                s0 = fmaf(qr[c].x, w.x, s0);
                s1 = fmaf(qr[c].y, w.y, s1);
                s2 = fmaf(qr[c].z, w.z, s2);
                s3 = fmaf(qr[c].w, w.w, s3);
            }
            Ps[qs][j] = ((s0 + s1) + (s2 + s3)) * scale;   // wave-coherent
        }

        // softmax over the 96 scores: re-read own 12 (static offsets)
        float raw[12];
        #pragma unroll
        for (int t = 0; t < 12; ++t) raw[t] = Ps[qs][t*8 + dl];
        float m = -INFINITY;
        #pragma unroll
        for (int t = 0; t < 12; ++t) m = fmaxf(m, raw[t]);
        #pragma unroll
        for (int o = 1; o < 8; o <<= 1) m = fmaxf(m, __shfl_xor(m, o));
        float l = 0.f;
        #pragma unroll
        for (int t = 0; t < 12; ++t) l += __expf(raw[t] - m);
        #pragma unroll
        for (int o = 1; o < 8; o <<= 1) l += __shfl_xor(l, o);
        const float inv = 1.0f / l;
        #pragma unroll
        for (int t = 0; t < 12; ++t) Ps[qs][t*8 + dl] = __expf(raw[t] - m) * inv;

        // phase 2: weighted V sum; p via LDS broadcast (no shuffles)
        float a0 = 0.f, a1 = 0.f, a2 = 0.f, a3 = 0.f;
        #pragma unroll 4
        for (int j = 0; j < TK; ++j) {
            const float p = Ps[qs][j];                       // 8-lane broadcast
            float4 vv = *(const float4*)&Vs[j*HD + dl*4];    // bcast across groups
            a0 = fmaf(p, vv.x, a0);
            a1 = fmaf(p, vv.y, a1);
            a2 = fmaf(p, vv.z, a2);
            a3 = fmaf(p, vv.w, a3);
        }

        if (act) {
            float* op = out + (b*NN + nn)*CC + hh*HD + dl*4;
            *(float4*)op = make_float4(a0, a1, a2, a3);
        }
    }
}

// ---------------------------------------------------------------------------
extern "C" void kernel_launch(void* const* d_in, const int* in_sizes, int n_in,
                              void* d_out, int out_size, void* d_ws, size_t ws_size,
                              hipStream_t stream)
{
    const float* x      = (const float*)d_in[0];   // [B,H,W,C] = [3200, 384]
    const float* w_qkv  = (const float*)d_in[1];   // [1152, 384]
    const float* w_gp   = (const float*)d_in[2];   // [48, 384] -> (12,48,32)
    const float* w_proj = (const float*)d_in[3];   // [384, 384]
    float* out = (float*)d_out;                    // [B,H,W,C]

    float* ws = (float*)d_ws;
    float* q        = ws;                 // [B,h,N,d] 1228800
    float* kk       = ws + 1228800;
    float* vv       = ws + 2457600;
    float* attn_out = ws + 3686400;       // [B,N,h*d] 1228800
    float* scores   = ws + 4915200;       // [1152][1600] 1843200
    float* qmean    = ws + 6758400;       // [1152][32]   36864
    int*   iws      = (int*)(ws + 6795264);
    int*   gidx     = iws;                // 38400
    int*   topk     = iws + 38400;        // 110592
    int*   qperm    = iws + 38400 + 110592;            // 38400
    int*   qoff     = iws + 38400 + 110592 + 38400;    // 1152
    int*   qcnt     = qoff + 1152;                     // 1152

    // 1) QKV projection — 900 blocks x 2 k-split waves
    gemm_w2<0><<<dim3(QKV_COLS/64, (NB*NN)/64), 128, 0, stream>>>(
        x, w_qkv, q, kk, vv, NB*NN, QKV_COLS, CC);

    // 2) query -> group routing
    group_route<<<NQ/256, 256, 0, stream>>>(q, w_gp, gidx);

    // 3a) deterministic group means (branchless) + query buckets
    qmean_all2<<<BHN*GN, 256, 0, stream>>>(q, gidx, qmean, qperm, qoff, qcnt);

    // 3b) group->key score matrix
    score_all<<<dim3(7, BHN), 256, 0, stream>>>(qmean, kk, scores);

    // 3c) per-wave barrier-free radix top-96
    topk_radix<<<(BHN*GN)/4, 256, 0, stream>>>(scores, topk);

    // 4) group-bucketed sparse attention, shuffle-free phase 1 (2304 blocks)
    sparse_attn8<<<BHN*GN*2, 256, 0, stream>>>(q, kk, vv, topk, qperm, qoff, qcnt, attn_out);

    // 5) output projection — 300 blocks x 2 k-split waves
    gemm_w2<1><<<dim3(CC/64, (NB*NN)/64), 128, 0, stream>>>(
        attn_out, w_proj, out, nullptr, nullptr, NB*NN, CC, CC);
}

// Round 7
// 256.953 us; speedup vs baseline: 2.1394x; 2.1394x over previous
//
#include <hip/hip_runtime.h>
#include <math.h>

#define NH 12
#define HD 32
#define GN 48
#define TK 96
#define NB 2
#define NN 1600
#define CC 384
#define BHN (NB*NH)          // 24
#define QKV_COLS (3*NH*HD)   // 1152
#define NQ (BHN*NN)          // 38400 total (b,h,n) queries
#define KP 36                // padded K row: bank-quad = 4*((row+chunk)%8)
#define LPW 68               // LDS row pad: 68%32=4 -> write/read aliasing is 2-way (free)
#define WREG (16*LPW*2)      // per-wave LDS region: As(16x68) + Bs(16x68) = 2176 floats

// ---------------------------------------------------------------------------
// GEMM-W2 (round 7): out = A[M,K] @ B[N,K]^T. 64x64 tile, 8x8 micro,
// TWO waves per block with K SPLIT ACROSS WAVES, each wave in its OWN LDS
// buffer -> zero barriers in the main loop; one 2-term reduction at the end.
//  - R6 FAILED on launch_bounds(128,2): VGPR clamped to 128 -> acc spilled
//    (FETCH 402MB / WRITE 691MB / VALUBusy 7%). Structure passed correctness.
//  - Fix: launch_bounds(128,1) -> 512-VGPR budget. Natural usage ~200 (R3
//    measured 196 for the same loop body) -> 2 waves/SIMD still co-resident
//    (2x196 <= 512). LDS 17.4KB/block is not the occupancy limiter.
//  - Model: 8x8 micro = 1 B/FMA-lane (LDS-balanced); 900 blocks x 2 waves
//    = 1.76 waves/SIMD of independent work.
// MODE 0: scatter epilogue into q/k/v [B,h,N,d]   MODE 1: plain store [M,N]
// ---------------------------------------------------------------------------
template<int MODE>
__global__ __launch_bounds__(128, 1)
void gemm_w2(const float* __restrict__ A, const float* __restrict__ B,
             float* __restrict__ o0, float* __restrict__ o1, float* __restrict__ o2,
             int M, int N, int K)
{
    __shared__ float S[2*WREG];       // [wave][As 16x68 | Bs 16x68], 17408 B
    const int tid = threadIdx.x;      // 0..127
    const int w = tid >> 6;           // wave 0/1
    const int lane = tid & 63;
    const int tx = lane & 7, ty = lane >> 3;
    const int m0 = blockIdx.y * 64, n0 = blockIdx.x * 64;

    float* __restrict__ As = S + w*WREG;            // As[k][r] = As[k*LPW + r]
    float* __restrict__ Bs = As + 16*LPW;

    const int KH = K >> 1;            // 192
    const int kbeg = w * KH;

    // staging map (R3-proven): thread covers row srow+16c, k-seg scol..scol+3
    const int srow = lane >> 2;       // 0..15
    const int scol = (lane & 3) * 4;  // 0,4,8,12
    const float* __restrict__ Ap = &A[(m0 + srow) * K + kbeg + scol];
    const float* __restrict__ Bp = &B[(n0 + srow) * K + kbeg + scol];
    const int rstep = 16 * K;

    float acc[8][8] = {};

    // prologue: stage tile 0 of this wave's k-range
    {
        #pragma unroll
        for (int c = 0; c < 4; ++c) {
            float4 a = *(const float4*)(Ap + c*rstep);
            float4 b = *(const float4*)(Bp + c*rstep);
            int r = c*16 + srow;
            As[(scol+0)*LPW + r] = a.x; As[(scol+1)*LPW + r] = a.y;
            As[(scol+2)*LPW + r] = a.z; As[(scol+3)*LPW + r] = a.w;
            Bs[(scol+0)*LPW + r] = b.x; Bs[(scol+1)*LPW + r] = b.y;
            Bs[(scol+2)*LPW + r] = b.z; Bs[(scol+3)*LPW + r] = b.w;
        }
    }
    // no barrier: each wave owns its buffer; DS ops wave-ordered

    for (int k0 = 16; k0 <= KH; k0 += 16) {
        // 1) issue next-tile global loads first — hide under the FMA block
        const bool more = (k0 < KH);
        float4 an[4], bn[4];
        if (more) {
            #pragma unroll
            for (int c = 0; c < 4; ++c) {
                an[c] = *(const float4*)(Ap + c*rstep + k0);
                bn[c] = *(const float4*)(Bp + c*rstep + k0);
            }
        }
        // 2) compute current tile: 16 kk x 64 FMA per lane, 4 ds_read_b128/kk
        #pragma unroll
        for (int kk = 0; kk < 16; ++kk) {
            float4 A0 = *(const float4*)&As[kk*LPW + ty*8];     // 8-addr bcast
            float4 A1 = *(const float4*)&As[kk*LPW + ty*8 + 4];
            float4 B0 = *(const float4*)&Bs[kk*LPW + tx*8];
            float4 B1 = *(const float4*)&Bs[kk*LPW + tx*8 + 4];
            float ar[8] = {A0.x, A0.y, A0.z, A0.w, A1.x, A1.y, A1.z, A1.w};
            float br[8] = {B0.x, B0.y, B0.z, B0.w, B1.x, B1.y, B1.z, B1.w};
            #pragma unroll
            for (int i = 0; i < 8; ++i)
                #pragma unroll
                for (int j = 0; j < 8; ++j)
                    acc[i][j] = fmaf(ar[i], br[j], acc[i][j]);
        }
        // 3) overwrite own buffer — wave-ordered DS, no barrier
        if (more) {
            #pragma unroll
            for (int c = 0; c < 4; ++c) {
                int r = c*16 + srow;
                As[(scol+0)*LPW + r] = an[c].x; As[(scol+1)*LPW + r] = an[c].y;
                As[(scol+2)*LPW + r] = an[c].z; As[(scol+3)*LPW + r] = an[c].w;
                Bs[(scol+0)*LPW + r] = bn[c].x; Bs[(scol+1)*LPW + r] = bn[c].y;
                Bs[(scol+2)*LPW + r] = bn[c].z; Bs[(scol+3)*LPW + r] = bn[c].w;
            }
        }
    }

    // ---- cross-wave reduction: out = acc_w0 + acc_w1 (fixed order) ----
    __syncthreads();                  // both waves done with tile buffers
    if (w == 1) {
        #pragma unroll
        for (int i = 0; i < 8; ++i)
            #pragma unroll
            for (int j = 0; j < 8; ++j)
                S[(i*8 + j)*64 + lane] = acc[i][j];   // bank = lane%32: free
    }
    __syncthreads();
    if (w == 1) return;

    #pragma unroll
    for (int i = 0; i < 8; ++i)
        #pragma unroll
        for (int j = 0; j < 8; ++j)
            acc[i][j] += S[(i*8 + j)*64 + lane];      // low-k + high-k

    if (MODE == 0) {
        // 64 | 384: the tile's 64 cols lie inside exactly one of q/k/v
        const int which = n0 / CC;
        const int rembase = n0 - which * CC + tx*8;
        float* __restrict__ dst = (which == 0) ? o0 : (which == 1) ? o1 : o2;
        #pragma unroll
        for (int i = 0; i < 8; ++i) {
            int row = m0 + ty*8 + i;
            int b  = row / NN;
            int nn = row - b * NN;
            #pragma unroll
            for (int jn = 0; jn < 2; ++jn) {
                int rem = rembase + jn*4;          // stays inside one head
                int hh = rem >> 5, dd = rem & 31;
                float4 st = make_float4(acc[i][jn*4+0], acc[i][jn*4+1],
                                        acc[i][jn*4+2], acc[i][jn*4+3]);
                *(float4*)&dst[((b*NH + hh)*NN + nn)*HD + dd] = st;
            }
        }
    } else {
        #pragma unroll
        for (int i = 0; i < 8; ++i) {
            int row = m0 + ty*8 + i;
            #pragma unroll
            for (int jn = 0; jn < 2; ++jn) {
                float4 st = make_float4(acc[i][jn*4+0], acc[i][jn*4+1],
                                        acc[i][jn*4+2], acc[i][jn*4+3]);
                *(float4*)&o0[row * N + n0 + tx*8 + jn*4] = st;
            }
        }
    }
}

// ---------------------------------------------------------------------------
// Kernel 2: per-query group argmax (gidx), strict > == jnp.argmax tie-break
// ---------------------------------------------------------------------------
__global__ __launch_bounds__(256)
void group_route(const float* __restrict__ q, const float* __restrict__ wgp,
                 int* __restrict__ gidx)
{
    int t = blockIdx.x * 256 + threadIdx.x;   // [0, NQ)
    int bh = t / NN;
    int hh = bh % NH;
    const float* qp = q + t * HD;
    float qr[HD];
    #pragma unroll
    for (int i = 0; i < HD; i += 4) {
        float4 x = *(const float4*)&qp[i];
        qr[i] = x.x; qr[i+1] = x.y; qr[i+2] = x.z; qr[i+3] = x.w;
    }
    float best = -INFINITY; int bg = 0;
    for (int g = 0; g < GN; ++g) {
        const float* gp = wgp + hh*GN*HD + g*HD;
        float s = 0.f;
        #pragma unroll
        for (int i = 0; i < HD; i += 4) {
            float4 w = *(const float4*)&gp[i];
            s += qr[i]*w.x + qr[i+1]*w.y + qr[i+2]*w.z + qr[i+3]*w.w;
        }
        if (s > best) { best = s; bg = g; }
    }
    gidx[t] = bg;
}

// ---------------------------------------------------------------------------
// Kernel 3a (v4): per-(bh,g) deterministic group-mean, branchless always-load
// + query bucketing (qperm/qoff/qcnt). 1152 blocks.
// ---------------------------------------------------------------------------
__global__ __launch_bounds__(256)
void qmean_all2(const float* __restrict__ q, const int* __restrict__ gidx,
                float* __restrict__ qmean, int* __restrict__ qperm,
                int* __restrict__ qoff, int* __restrict__ qcnt)
{
    __shared__ float part[8][HD];
    __shared__ int   cnts[8];
    __shared__ int   off_s, pos_s;
    const int bid = blockIdx.x;       // bh*GN + g
    const int g = bid % GN, bh = bid / GN;
    const int tid = threadIdx.x;
    const int s = tid >> 5, dd = tid & 31;

    const int* __restrict__ gx = gidx + bh*NN;
    const float* __restrict__ qb = q + bh*NN*HD;

    if (tid == 0) { off_s = 0; pos_s = 0; }

    const int base = s * 200;         // 1600/8 rows per slice, contiguous
    float p = 0.f; int c = 0;
    #pragma unroll 2
    for (int n0 = 0; n0 < 200; n0 += 4) {
        int4 g4 = *(const int4*)&gx[base + n0];
        float v0 = qb[(base+n0+0)*HD + dd];   // unconditional: pipelines
        float v1 = qb[(base+n0+1)*HD + dd];
        float v2 = qb[(base+n0+2)*HD + dd];
        float v3 = qb[(base+n0+3)*HD + dd];
        if (g4.x == g) { p += v0; c++; }      // cndmask+add, no branch
        if (g4.y == g) { p += v1; c++; }
        if (g4.z == g) { p += v2; c++; }
        if (g4.w == g) { p += v3; c++; }
    }
    part[s][dd] = p;
    if (dd == 0) cnts[s] = c;
    __syncthreads();                  // part[] + off_s/pos_s init visible

    if (tid < HD) {
        float sum = 0.f; int ct = 0;
        #pragma unroll
        for (int ss = 0; ss < 8; ++ss) { sum += part[ss][tid]; ct += cnts[ss]; }
        qmean[bid*HD + tid] = ct ? sum / (float)ct : 0.f;
    }

    // bucketing: offset = #queries in groups < g (gx row is L1-hot now)
    int mo = 0;
    for (int n = tid; n < NN; n += 256) mo += (gx[n] < g);
    atomicAdd(&off_s, mo);
    __syncthreads();
    for (int n = tid; n < NN; n += 256) {
        if (gx[n] == g) {
            int pp = atomicAdd(&pos_s, 1);
            qperm[bh*NN + off_s + pp] = n;
        }
    }
    __syncthreads();
    if (tid == 0) { qoff[bid] = off_s; qcnt[bid] = pos_s; }
}

// ---------------------------------------------------------------------------
// Kernel 3b: scores[bh*GN+g][n] = qmean[bh,g] . k[bh,n]. Thread owns one n,
// k-row in registers, qmean tile in LDS (broadcast reads), coalesced stores.
// ---------------------------------------------------------------------------
__global__ __launch_bounds__(256)
void score_all(const float* __restrict__ qmean, const float* __restrict__ k,
               float* __restrict__ scores)
{
    __shared__ float Qs[GN][HD];          // 6 KB
    const int bh = blockIdx.y;
    const int tid = threadIdx.x;
    const int n = blockIdx.x*256 + tid;
    for (int i = tid; i < GN*HD; i += 256)
        ((float*)Qs)[i] = qmean[bh*GN*HD + i];
    __syncthreads();
    if (n >= NN) return;
    const float* __restrict__ kp = k + (bh*NN + n)*HD;
    float4 kr[8];
    #pragma unroll
    for (int c = 0; c < 8; ++c) kr[c] = *(const float4*)&kp[c*4];
    for (int g = 0; g < GN; ++g) {
        float s = 0.f;
        #pragma unroll
        for (int c = 0; c < 8; ++c) {
            float4 qv = *(const float4*)&Qs[g][c*4];   // same-addr broadcast
            s += kr[c].x*qv.x + kr[c].y*qv.y + kr[c].z*qv.z + kr[c].w*qv.w;
        }
        scores[(bh*GN + g)*NN + n] = s;               // coalesced per g
    }
}

// ---------------------------------------------------------------------------
// Kernel 3c: per-WAVE barrier-free radix top-96. Each 64-lane wave owns one
// (bh,g) row of 1600 scores: keys + 256-bin hist live in per-wave LDS slices
// (DS ops from a wave complete in program order -> no __syncthreads).
// Suffix-scan in registers via shfl; pivot via ballot; collect via ballot-
// compaction in ascending index order (== lax.top_k lowest-index ties).
// ---------------------------------------------------------------------------
__global__ __launch_bounds__(256)
void topk_radix(const float* __restrict__ scores, int* __restrict__ topk)
{
    __shared__ unsigned keysL[4][NN];     // 25.6 KB
    __shared__ unsigned histL[4][256];    // 4 KB
    const int tid = threadIdx.x;
    const int w = tid >> 6, lane = tid & 63;
    const int gid = blockIdx.x*4 + w;     // (bh*GN + g) in [0,1152)
    const float* __restrict__ row = scores + gid*NN;
    unsigned* keys = keysL[w];
    unsigned* hist = histL[w];

    // load + order-preserving transform (1600 = 25*64 exactly)
    #pragma unroll
    for (int i = 0; i < 25; ++i) {
        int m = lane + 64*i;
        unsigned u = __float_as_uint(row[m]);
        u = (u & 0x80000000u) ? ~u : (u | 0x80000000u);
        keys[m] = u;
    }

    unsigned prefix = 0, r = TK;
    #pragma unroll
    for (int pass = 0; pass < 4; ++pass) {
        const int shift = 24 - 8*pass;
        #pragma unroll
        for (int j = 0; j < 4; ++j) hist[lane*4 + j] = 0;
        #pragma unroll
        for (int i = 0; i < 25; ++i) {
            unsigned u = keys[lane + 64*i];
            bool match = (pass == 0) || ((u >> (shift+8)) == (prefix >> (shift+8)));
            if (match) atomicAdd(&hist[(u >> shift) & 255u], 1u);
        }
        // suffix scan: lane holds bins 4L..4L+3
        uint4 h = *(const uint4*)&hist[lane*4];
        unsigned s3 = h.w, s2 = h.z + s3, s1 = h.y + s2, s0 = h.x + s1;
        unsigned I = s0;                      // inclusive suffix over lane totals
        #pragma unroll
        for (int off = 1; off < 64; off <<= 1) {
            unsigned t = __shfl_down(I, off);
            if (lane + off < 64) I += t;
        }
        unsigned E = I - s0;                  // strict suffix (lanes > L)
        unsigned sf[5] = {E+s0, E+s1, E+s2, E+s3, E};
        int bj = -1; unsigned subc = 0;
        #pragma unroll
        for (int j = 0; j < 4; ++j)
            if (sf[j] >= r && sf[j+1] < r) { bj = j; subc = sf[j+1]; }
        unsigned long long mask = __ballot(bj >= 0);   // exactly one bit set
        int src = __ffsll(mask) - 1;
        int bstar = __shfl(lane*4 + bj, src);
        unsigned sub = (unsigned)__shfl((int)subc, src);
        prefix |= ((unsigned)bstar) << shift;
        r -= sub;
    }
    const unsigned P = prefix;   // exact 96th-largest key; r = #equals to take

    // collect: all keys > P, then first r keys == P (ascending index)
    int* tko = topk + gid*TK;
    int base = 0;
    #pragma unroll
    for (int i = 0; i < 25; ++i) {
        int m = lane + 64*i;
        bool gt = (keys[m] > P);
        unsigned long long mask = __ballot(gt);
        if (gt) tko[base + __popcll(mask & ((1ull << lane) - 1ull))] = m;
        base += (int)__popcll(mask);
    }
    #pragma unroll
    for (int i = 0; i < 25; ++i) {
        int m = lane + 64*i;
        bool eq = (keys[m] == P);
        unsigned long long mask = __ballot(eq);
        if (eq) {
            int pos = base + (int)__popcll(mask & ((1ull << lane) - 1ull));
            if (pos < TK) tko[pos] = m;
        }
        base += (int)__popcll(mask);
    }
}

// ---------------------------------------------------------------------------
// Kernel 4 (v8): group-bucketed attention, shuffle-free phase 1 (padded Ks),
// LDS score buffer Ps, split-S. Verified round 12: dropped out of top-5.
// ---------------------------------------------------------------------------
__global__ __launch_bounds__(256)
void sparse_attn8(const float* __restrict__ q, const float* __restrict__ k,
                  const float* __restrict__ v, const int* __restrict__ topk,
                  const int* __restrict__ qperm, const int* __restrict__ qoff,
                  const int* __restrict__ qcnt, float* __restrict__ out)
{
    __shared__ float Ks[TK*KP];      // 13.8 KB (padded rows)
    __shared__ float Vs[TK*HD];      // 12 KB
    __shared__ float Ps[32][104];    // 13.3 KB, padded row (104%32==8)

    const int sub = blockIdx.x & 1;       // split-S half
    const int bid = blockIdx.x >> 1;      // bh*GN + g
    const int bh = bid / GN;
    const int nq = qcnt[bid];
    if (nq <= sub*32) return;             // this half has no work (uniform)
    const int off = qoff[bid];
    const int tid = threadIdx.x;

    const int* __restrict__ tk = topk + bid*TK;
    const float* __restrict__ kb = k + bh*NN*HD;
    const float* __restrict__ vb = v + bh*NN*HD;

    // stage K (padded) and V: 8 consecutive lanes fetch one 128B row
    for (int idx = tid; idx < TK*8; idx += 256) {
        int row = idx >> 3, ch = idx & 7;
        int r = tk[row];
        *(float4*)&Ks[row*KP + ch*4] = *(const float4*)&kb[r*HD + ch*4];
        ((float4*)Vs)[idx] = *(const float4*)&vb[r*HD + ch*4];
    }
    __syncthreads();

    const float scale = 0.17677669529663687f;   // 32^-0.5
    const int qs = tid >> 3;            // query slot 0..31 (Ps row owner)
    const int dl = tid & 7;             // lane in 8-lane group
    const int b = bh / NH, hh = bh - b*NH;
    const float* __restrict__ qbase = q + bh*NN*HD;
    const int* __restrict__ qlist = qperm + bh*NN + off;

    for (int it0 = sub*32; it0 < nq; it0 += 64) {
        const int qi = it0 + qs;
        const bool act = (qi < nq);
        const int nn = qlist[act ? qi : nq-1];   // safe clamp; group-uniform

        // full q row (8-lane same-address reads: one cache line per group)
        float4 qr[8];
        #pragma unroll
        for (int c = 0; c < 8; ++c) qr[c] = *(const float4*)&qbase[nn*HD + c*4];

        // phase 1: lane dl fully scores keys t*8+dl -> Ps[qs][j]; no shuffles
        #pragma unroll 2
        for (int t = 0; t < 12; ++t) {
            const int j = t*8 + dl;
            float s0 = 0.f, s1 = 0.f, s2 = 0.f, s3 = 0.f;
            #pragma unroll
            for (int c = 0; c < 8; ++c) {
                float4 w = *(const float4*)&Ks[j*KP + c*4];
                s0 = fmaf(qr[c].x, w.x, s0);
                s1 = fmaf(qr[c].y, w.y, s1);
                s2 = fmaf(qr[c].z, w.z, s2);
                s3 = fmaf(qr[c].w, w.w, s3);
            }
            Ps[qs][j] = ((s0 + s1) + (s2 + s3)) * scale;   // wave-coherent
        }

        // softmax over the 96 scores: re-read own 12 (static offsets)
        float raw[12];
        #pragma unroll
        for (int t = 0; t < 12; ++t) raw[t] = Ps[qs][t*8 + dl];
        float m = -INFINITY;
        #pragma unroll
        for (int t = 0; t < 12; ++t) m = fmaxf(m, raw[t]);
        #pragma unroll
        for (int o = 1; o < 8; o <<= 1) m = fmaxf(m, __shfl_xor(m, o));
        float l = 0.f;
        #pragma unroll
        for (int t = 0; t < 12; ++t) l += __expf(raw[t] - m);
        #pragma unroll
        for (int o = 1; o < 8; o <<= 1) l += __shfl_xor(l, o);
        const float inv = 1.0f / l;
        #pragma unroll
        for (int t = 0; t < 12; ++t) Ps[qs][t*8 + dl] = __expf(raw[t] - m) * inv;

        // phase 2: weighted V sum; p via LDS broadcast (no shuffles)
        float a0 = 0.f, a1 = 0.f, a2 = 0.f, a3 = 0.f;
        #pragma unroll 4
        for (int j = 0; j < TK; ++j) {
            const float p = Ps[qs][j];                       // 8-lane broadcast
            float4 vv = *(const float4*)&Vs[j*HD + dl*4];    // bcast across groups
            a0 = fmaf(p, vv.x, a0);
            a1 = fmaf(p, vv.y, a1);
            a2 = fmaf(p, vv.z, a2);
            a3 = fmaf(p, vv.w, a3);
        }

        if (act) {
            float* op = out + (b*NN + nn)*CC + hh*HD + dl*4;
            *(float4*)op = make_float4(a0, a1, a2, a3);
        }
    }
}

// ---------------------------------------------------------------------------
extern "C" void kernel_launch(void* const* d_in, const int* in_sizes, int n_in,
                              void* d_out, int out_size, void* d_ws, size_t ws_size,
                              hipStream_t stream)
{
    const float* x      = (const float*)d_in[0];   // [B,H,W,C] = [3200, 384]
    const float* w_qkv  = (const float*)d_in[1];   // [1152, 384]
    const float* w_gp   = (const float*)d_in[2];   // [48, 384] -> (12,48,32)
    const float* w_proj = (const float*)d_in[3];   // [384, 384]
    float* out = (float*)d_out;                    // [B,H,W,C]

    float* ws = (float*)d_ws;
    float* q        = ws;                 // [B,h,N,d] 1228800
    float* kk       = ws + 1228800;
    float* vv       = ws + 2457600;
    float* attn_out = ws + 3686400;       // [B,N,h*d] 1228800
    float* scores   = ws + 4915200;       // [1152][1600] 1843200
    float* qmean    = ws + 6758400;       // [1152][32]   36864
    int*   iws      = (int*)(ws + 6795264);
    int*   gidx     = iws;                // 38400
    int*   topk     = iws + 38400;        // 110592
    int*   qperm    = iws + 38400 + 110592;            // 38400
    int*   qoff     = iws + 38400 + 110592 + 38400;    // 1152
    int*   qcnt     = qoff + 1152;                     // 1152

    // 1) QKV projection — 900 blocks x 2 k-split waves
    gemm_w2<0><<<dim3(QKV_COLS/64, (NB*NN)/64), 128, 0, stream>>>(
        x, w_qkv, q, kk, vv, NB*NN, QKV_COLS, CC);

    // 2) query -> group routing
    group_route<<<NQ/256, 256, 0, stream>>>(q, w_gp, gidx);

    // 3a) deterministic group means (branchless) + query buckets
    qmean_all2<<<BHN*GN, 256, 0, stream>>>(q, gidx, qmean, qperm, qoff, qcnt);

    // 3b) group->key score matrix
    score_all<<<dim3(7, BHN), 256, 0, stream>>>(qmean, kk, scores);

    // 3c) per-wave barrier-free radix top-96
    topk_radix<<<(BHN*GN)/4, 256, 0, stream>>>(scores, topk);

    // 4) group-bucketed sparse attention, shuffle-free phase 1 (2304 blocks)
    sparse_attn8<<<BHN*GN*2, 256, 0, stream>>>(q, kk, vv, topk, qperm, qoff, qcnt, attn_out);

    // 5) output projection — 300 blocks x 2 k-split waves
    gemm_w2<1><<<dim3(CC/64, (NB*NN)/64), 128, 0, stream>>>(
        attn_out, w_proj, out, nullptr, nullptr, NB*NN, CC, CC);
}